// Round 1
// 247.278 us; speedup vs baseline: 1.0188x; 1.0188x over previous
//
#include <hip/hip_runtime.h>
#include <cstdint>
#include <cstddef>

typedef unsigned short ushort_t;
typedef __attribute__((ext_vector_type(8))) short bf16x8;
typedef __attribute__((ext_vector_type(4))) float f32x4;

#define MROWS 16384
#define KDIM  1024
#define NDIM  2048
#define HDIM  512
#define NTILE 16            // K tiles of 64

static __device__ __forceinline__ unsigned short f2bf(float f) {
    unsigned int u = __float_as_uint(f);
    u += 0x7fffu + ((u >> 16) & 1u);   // round-to-nearest-even
    return (unsigned short)(u >> 16);
}

static __device__ __forceinline__ float sigmoid_f(float x) {
    return 1.0f / (1.0f + __expf(-x));
}
static __device__ __forceinline__ float tanh_f(float x) {
    float t = __expf(2.0f * x);
    return 1.0f - 2.0f / (t + 1.0f);   // saturates cleanly at +/-1 for large |x|
}

// ---------------------------------------------------------------------------
// Pass 0 (merged): blocks [0,8192): A = bf16(concat(x,h_prev)) [16384][1024]
//                  blocks [8192,8704): Bt via LDS transpose
//                  Bt[n'][k] = bf16(Wcat[k][col]), n' = 4h+g, col = g*512+h
// ---------------------------------------------------------------------------
__global__ __launch_bounds__(256) void pack_ab(const float* __restrict__ x,
                                               const float* __restrict__ hp,
                                               const float* __restrict__ Wi,
                                               const float* __restrict__ Wh,
                                               ushort_t* __restrict__ A,
                                               ushort_t* __restrict__ Bt) {
    __shared__ ushort_t sm[64][72];                 // pack_b transpose tile (+8 pad)
    const int tid = threadIdx.x;
    if (blockIdx.x < 8192) {
        int t = blockIdx.x * 256 + tid;             // 8 elems per thread
        int row = t >> 7;
        int kc = (t & 127) << 3;                    // wave-uniform x vs hp branch
        const float* src = (kc < 512) ? (x + (size_t)row * 512 + kc)
                                      : (hp + (size_t)row * 512 + (kc - 512));
        float4 v0 = ((const float4*)src)[0];
        float4 v1 = ((const float4*)src)[1];
        ushort_t o[8] __attribute__((aligned(16)));
        o[0] = f2bf(v0.x); o[1] = f2bf(v0.y); o[2] = f2bf(v0.z); o[3] = f2bf(v0.w);
        o[4] = f2bf(v1.x); o[5] = f2bf(v1.y); o[6] = f2bf(v1.z); o[7] = f2bf(v1.w);
        *((uint4*)(A + (size_t)row * KDIM + kc)) = *((const uint4*)o);
    } else {
        int b2 = blockIdx.x - 8192;                 // 0..511
        int kt = b2 >> 5;                           // k-tile 0..15 (64 rows each)
        int ct = b2 & 31;                           // col-tile 0..31 (64 cols each)
        const float* W = (kt < 8) ? (Wi + (size_t)(kt * 64) * NDIM)
                                  : (Wh + (size_t)((kt - 8) * 64) * NDIM);
        // coalesced 64x64 fp32 tile load -> bf16 LDS
        int c0 = (tid & 15) * 4;
        int r0 = tid >> 4;                          // 0..15
#pragma unroll
        for (int r = 0; r < 4; ++r) {
            int krow = r * 16 + r0;
            float4 v = *((const float4*)(W + (size_t)krow * NDIM + ct * 64 + c0));
            sm[krow][c0 + 0] = f2bf(v.x);
            sm[krow][c0 + 1] = f2bf(v.y);
            sm[krow][c0 + 2] = f2bf(v.z);
            sm[krow][c0 + 3] = f2bf(v.w);
        }
        __syncthreads();
        int g = (ct * 64) >> 9;                     // gate 0..3 (tile never spans g)
        int h0 = ct * 64 - g * 512;
#pragma unroll
        for (int q = tid; q < 512; q += 256) {
            int cc = q >> 3;                        // col within tile
            int kc = (q & 7) * 8;                   // k chunk within tile
            ushort_t o[8] __attribute__((aligned(16)));
#pragma unroll
            for (int j = 0; j < 8; ++j) o[j] = sm[kc + j][cc];
            int np = 4 * (h0 + cc) + g;
            *((uint4*)(Bt + (size_t)np * KDIM + kt * 64 + kc)) = *((const uint4*)o);
        }
    }
}

// ---------------------------------------------------------------------------
// Pass 1: 256x256-tile bf16 MFMA GEMM [M=16384,K=1024] x [N'=2048,K]^T.
// 8 waves (2M x 4N), each owning a 128x64 wave tile (acc 8x4 f32x4 = 128 regs).
// 8-phase-style schedule: 4 compute phases per K-tile (2 barriers each,
// setprio around MFMA clusters), double-buffered 128 KB LDS, staging issued
// a FULL K-tile ahead at the tile boundary with counted s_waitcnt vmcnt(8)
// (never 0 in steady state).  XOR chunk swizzle (proven 0-conflict) on both
// the pre-swizzled global source and the ds_read side.
//
// Sync invariants:
//  - tile t computes from buf[t&1]; STAGE(t+2) -> buf[t&1] is issued only
//    after tile t's closing "lgkmcnt(0); s_barrier" (all waves' ds_reads of
//    that buffer retired => no write-under-read race).
//  - vmcnt(8) after STAGE(t+2) leaves exactly tile t+2's 8 loads in flight
//    and guarantees tile t+1 (issued one boundary earlier) has landed;
//    the fused s_barrier publishes that guarantee workgroup-wide.
//  - all waits are single asm volatile blocks with "memory" clobbers so no
//    LDS access or global_load_lds crosses them at compile time.
// ---------------------------------------------------------------------------
__global__ __launch_bounds__(512, 2) void gemm_cell(const ushort_t* __restrict__ A,
                                                    const ushort_t* __restrict__ Bt,
                                                    const float* __restrict__ b,
                                                    const float* __restrict__ c_prev,
                                                    float* __restrict__ h_out,
                                                    float* __restrict__ c_out) {
    __shared__ ushort_t lds[2][32768];             // 128 KB: per buf A 32KB + B 32KB

    const int tid  = threadIdx.x;
    const int w    = tid >> 6;
    const int lane = tid & 63;
    const int mi   = w >> 2;                       // 0..1  (M wave row)
    const int nj   = w & 3;                        // 0..3  (N wave col)
    // XCD-aware swizzle: 512 blocks, 512%8==0 -> bijective
    int bid = blockIdx.x;
    int lid = (bid & 7) * 64 + (bid >> 3);
    const int m0 = (lid >> 3) * 256;               // 64 m-tiles
    const int n0 = (lid & 7) * 256;                // 8 n-tiles (permuted N)
    const int lr   = lane & 15;
    const int quad = lane >> 4;
    const int sw   = lr & 7;                       // read-side swizzle key

    // per-thread staging constants: slot c = r*512+tid; trow = r*64 + tid>>3;
    // stored chunk cs holds global chunk cs ^ (trow&7); both r*512 and r*64
    // are 0 mod 8 so the XOR key is r-independent.
    const int trow0 = tid >> 3;
    const int chg   = (tid & 7) ^ (trow0 & 7);
    const size_t a_base = (size_t)(m0 + trow0) * KDIM + chg * 8;
    const size_t b_base = (size_t)(n0 + trow0) * KDIM + chg * 8;
    const int    l_base = tid * 16;                // byte offset, lane-linear x16

#define STAGE(kt, bufi) do {                                                        \
    const ushort_t* ap_ = A + a_base + (size_t)(kt) * 64;                           \
    const ushort_t* bp_ = Bt + b_base + (size_t)(kt) * 64;                          \
    char* al_ = (char*)&lds[bufi][0];                                               \
    char* bl_ = (char*)&lds[bufi][16384];                                           \
    _Pragma("unroll")                                                               \
    for (int r_ = 0; r_ < 4; ++r_)                                                  \
        __builtin_amdgcn_global_load_lds(                                           \
            (const __attribute__((address_space(1))) void*)(ap_ + (size_t)r_ * 64 * KDIM), \
            (__attribute__((address_space(3))) void*)(al_ + l_base + r_ * 8192),    \
            16, 0, 0);                                                              \
    _Pragma("unroll")                                                               \
    for (int r_ = 0; r_ < 4; ++r_)                                                  \
        __builtin_amdgcn_global_load_lds(                                           \
            (const __attribute__((address_space(1))) void*)(bp_ + (size_t)r_ * 64 * KDIM), \
            (__attribute__((address_space(3))) void*)(bl_ + l_base + r_ * 8192),    \
            16, 0, 0);                                                              \
} while (0)

    f32x4 acc[8][4];
#pragma unroll
    for (int i = 0; i < 8; ++i)
#pragma unroll
        for (int j = 0; j < 4; ++j) acc[i][j] = (f32x4){0.f, 0.f, 0.f, 0.f};

    // prologue: tiles 0,1 in flight; guarantee tile 0, leave tile 1's 8 loads out
    STAGE(0, 0);
    STAGE(1, 1);
    asm volatile("s_waitcnt vmcnt(8)\n\ts_barrier" ::: "memory");

#pragma unroll 2
    for (int t = 0; t < NTILE; ++t) {
        const ushort_t* Ab = &lds[t & 1][0];
        const ushort_t* Bb = &lds[t & 1][16384];
        bf16x8 af[4], bfr[4];

        // ---------- phase 1: kk=0, m-frags 0-3 (+ B kk=0) ----------
#pragma unroll
        for (int t2 = 0; t2 < 4; ++t2) {
            int ra = mi * 128 + t2 * 16 + lr;      // ra&7 == lr&7
            af[t2] = *((const bf16x8*)(Ab + (ra * 8 + (quad ^ sw)) * 8));
        }
#pragma unroll
        for (int t3 = 0; t3 < 4; ++t3) {
            int rb = nj * 64 + t3 * 16 + lr;
            bfr[t3] = *((const bf16x8*)(Bb + (rb * 8 + (quad ^ sw)) * 8));
        }
        __builtin_amdgcn_s_barrier();
        __builtin_amdgcn_s_setprio(1);
#pragma unroll
        for (int tm = 0; tm < 4; ++tm)
#pragma unroll
            for (int tn = 0; tn < 4; ++tn)
                acc[tm][tn] = __builtin_amdgcn_mfma_f32_16x16x32_bf16(
                    af[tm], bfr[tn], acc[tm][tn], 0, 0, 0);
        __builtin_amdgcn_s_setprio(0);
        __builtin_amdgcn_s_barrier();

        // ---------- phase 2: kk=0, m-frags 4-7 ----------
#pragma unroll
        for (int t2 = 0; t2 < 4; ++t2) {
            int ra = mi * 128 + (t2 + 4) * 16 + lr;
            af[t2] = *((const bf16x8*)(Ab + (ra * 8 + (quad ^ sw)) * 8));
        }
        __builtin_amdgcn_s_barrier();
        __builtin_amdgcn_s_setprio(1);
#pragma unroll
        for (int tm = 0; tm < 4; ++tm)
#pragma unroll
            for (int tn = 0; tn < 4; ++tn)
                acc[tm + 4][tn] = __builtin_amdgcn_mfma_f32_16x16x32_bf16(
                    af[tm], bfr[tn], acc[tm + 4][tn], 0, 0, 0);
        __builtin_amdgcn_s_setprio(0);
        __builtin_amdgcn_s_barrier();

        // ---------- phase 3: kk=1, m-frags 0-3 (+ B kk=1) ----------
#pragma unroll
        for (int t2 = 0; t2 < 4; ++t2) {
            int ra = mi * 128 + t2 * 16 + lr;
            af[t2] = *((const bf16x8*)(Ab + (ra * 8 + ((4 + quad) ^ sw)) * 8));
        }
#pragma unroll
        for (int t3 = 0; t3 < 4; ++t3) {
            int rb = nj * 64 + t3 * 16 + lr;
            bfr[t3] = *((const bf16x8*)(Bb + (rb * 8 + ((4 + quad) ^ sw)) * 8));
        }
        __builtin_amdgcn_s_barrier();
        __builtin_amdgcn_s_setprio(1);
#pragma unroll
        for (int tm = 0; tm < 4; ++tm)
#pragma unroll
            for (int tn = 0; tn < 4; ++tn)
                acc[tm][tn] = __builtin_amdgcn_mfma_f32_16x16x32_bf16(
                    af[tm], bfr[tn], acc[tm][tn], 0, 0, 0);
        __builtin_amdgcn_s_setprio(0);
        __builtin_amdgcn_s_barrier();

        // ---------- phase 4: kk=1, m-frags 4-7 ----------
#pragma unroll
        for (int t2 = 0; t2 < 4; ++t2) {
            int ra = mi * 128 + (t2 + 4) * 16 + lr;
            af[t2] = *((const bf16x8*)(Ab + (ra * 8 + ((4 + quad) ^ sw)) * 8));
        }
        __builtin_amdgcn_s_barrier();
        __builtin_amdgcn_s_setprio(1);
#pragma unroll
        for (int tm = 0; tm < 4; ++tm)
#pragma unroll
            for (int tn = 0; tn < 4; ++tn)
                acc[tm + 4][tn] = __builtin_amdgcn_mfma_f32_16x16x32_bf16(
                    af[tm], bfr[tn], acc[tm + 4][tn], 0, 0, 0);
        __builtin_amdgcn_s_setprio(0);
        // closing barrier: drain this wave's ds_reads so the buffer we are
        // about to overwrite (STAGE t+2) is provably free workgroup-wide.
        asm volatile("s_waitcnt lgkmcnt(0)\n\ts_barrier" ::: "memory");

        if (t < NTILE - 2) {
            STAGE(t + 2, t & 1);                   // buf just freed by tile t
            // guarantee tile t+1 landed; keep t+2's 8 loads in flight
            asm volatile("s_waitcnt vmcnt(8)\n\ts_barrier" ::: "memory");
        } else if (t == NTILE - 2) {
            // tail: nothing newer issued -> drain to guarantee tile NTILE-1
            asm volatile("s_waitcnt vmcnt(0)\n\ts_barrier" ::: "memory");
        }
        // t == NTILE-1: fall through to epilogue (all loads drained, all
        // reads retired at the closing lgkmcnt(0)+barrier above)
    }
#undef STAGE

    // ---- barrier-free epilogue: per-wave private 4 KB scratch ----
    // wave tile = 128 rows x 64 cols (16 h-indices); 8 chunks of 16 rows.
    // scratch lives in buf0 (last read by tile 14, retired at its barrier).
    float* scr = (float*)&lds[0][0] + w * 1024;    // 16 rows x 64 cols
    const int rr = lane >> 2;                      // row within chunk
    const int hg0 = ((n0 + nj * 64) >> 2) + (lane & 3) * 4;  // 4 consecutive h
    const float4 bi4 = *((const float4*)(b + hg0));
    const float4 bff = *((const float4*)(b + 512 + hg0));
    const float4 bgg = *((const float4*)(b + 1024 + hg0));
    const float4 boo = *((const float4*)(b + 1536 + hg0));
    const float bi[4] = {bi4.x, bi4.y, bi4.z, bi4.w};
    const float bfv[4] = {bff.x, bff.y, bff.z, bff.w};
    const float bg[4] = {bgg.x, bgg.y, bgg.z, bgg.w};
    const float bo[4] = {boo.x, boo.y, boo.z, boo.w};

#pragma unroll
    for (int tm = 0; tm < 8; ++tm) {
        // write 16x64 chunk, XOR-swizzled 16B col-blocks
#pragma unroll
        for (int tn = 0; tn < 4; ++tn) {
            int c = tn * 16 + lr;
#pragma unroll
            for (int rg = 0; rg < 4; ++rg) {
                int r = quad * 4 + rg;
                int blk = (c >> 2) ^ r;            // 0..15
                scr[r * 64 + blk * 4 + (c & 3)] = acc[tm][tn][rg];
            }
        }
        // same-wave in-order DS pipe: no barrier needed
        float4 gv[4];
#pragma unroll
        for (int j = 0; j < 4; ++j) {
            int cb = (lane & 3) * 4 + j;
            gv[j] = *((const float4*)(scr + rr * 64 + (cb ^ rr) * 4));
        }
        int grow = m0 + mi * 128 + tm * 16 + rr;
        float4 cp4 = *((const float4*)(c_prev + (size_t)grow * HDIM + hg0));
        const float cpv[4] = {cp4.x, cp4.y, cp4.z, cp4.w};
        float cn[4], hv[4];
#pragma unroll
        for (int j = 0; j < 4; ++j) {
            float iv = sigmoid_f(gv[j].x + bi[j]);
            float fv = sigmoid_f(gv[j].y + bfv[j]);
            float g2 = tanh_f(gv[j].z + bg[j]);
            float ov = sigmoid_f(gv[j].w + bo[j]);
            cn[j] = fv * cpv[j] + iv * g2;
            hv[j] = ov * tanh_f(cn[j]);
        }
        float4 cno = {cn[0], cn[1], cn[2], cn[3]};
        float4 hvo = {hv[0], hv[1], hv[2], hv[3]};
        *((float4*)(c_out + (size_t)grow * HDIM + hg0)) = cno;
        *((float4*)(h_out + (size_t)grow * HDIM + hg0)) = hvo;
    }
}

// ---------------------------------------------------------------------------
// Pass 2: in-place row-wise LayerNorm on h (one wave per 512-elem row)
// ---------------------------------------------------------------------------
__global__ __launch_bounds__(256) void ln_kernel(float* __restrict__ h,
                                                 const float* __restrict__ lw,
                                                 const float* __restrict__ lb) {
    int w = threadIdx.x >> 6;
    int lane = threadIdx.x & 63;
    int row = blockIdx.x * 4 + w;
    float* p = h + (size_t)row * HDIM + lane * 8;
    float4 a = ((const float4*)p)[0];
    float4 c = ((const float4*)p)[1];
    float s  = a.x + a.y + a.z + a.w + c.x + c.y + c.z + c.w;
    float ss = a.x * a.x + a.y * a.y + a.z * a.z + a.w * a.w +
               c.x * c.x + c.y * c.y + c.z * c.z + c.w * c.w;
#pragma unroll
    for (int off = 32; off > 0; off >>= 1) {
        s  += __shfl_xor(s, off);
        ss += __shfl_xor(ss, off);
    }
    float mu = s * (1.0f / 512.0f);
    float var = ss * (1.0f / 512.0f) - mu * mu;
    float rstd = rsqrtf(var + 1e-5f);
    const float* wp = lw + lane * 8;
    const float* bp = lb + lane * 8;
    float4 w0 = ((const float4*)wp)[0];
    float4 w1 = ((const float4*)wp)[1];
    float4 b0 = ((const float4*)bp)[0];
    float4 b1 = ((const float4*)bp)[1];
    a.x = (a.x - mu) * rstd * w0.x + b0.x;
    a.y = (a.y - mu) * rstd * w0.y + b0.y;
    a.z = (a.z - mu) * rstd * w0.z + b0.z;
    a.w = (a.w - mu) * rstd * w0.w + b0.w;
    c.x = (c.x - mu) * rstd * w1.x + b1.x;
    c.y = (c.y - mu) * rstd * w1.y + b1.y;
    c.z = (c.z - mu) * rstd * w1.z + b1.z;
    c.w = (c.w - mu) * rstd * w1.w + b1.w;
    ((float4*)p)[0] = a;
    ((float4*)p)[1] = c;
}

extern "C" void kernel_launch(void* const* d_in, const int* in_sizes, int n_in,
                              void* d_out, int out_size, void* d_ws, size_t ws_size,
                              hipStream_t stream) {
    const float* x      = (const float*)d_in[0];
    const float* h_prev = (const float*)d_in[1];
    const float* c_prev = (const float*)d_in[2];
    const float* W_i    = (const float*)d_in[3];
    const float* W_h    = (const float*)d_in[4];
    const float* b      = (const float*)d_in[5];
    const float* ln_w   = (const float*)d_in[6];
    const float* ln_b   = (const float*)d_in[7];

    float* h_out = (float*)d_out;                       // [16384][512]
    float* c_out = h_out + (size_t)MROWS * HDIM;        // [16384][512]

    ushort_t* A  = (ushort_t*)d_ws;                     // 32 MB
    ushort_t* Bt = A + (size_t)MROWS * KDIM;            // 4 MB

    pack_ab<<<8192 + 512, 256, 0, stream>>>(x, h_prev, W_i, W_h, A, Bt);
    gemm_cell<<<512, 512, 0, stream>>>(A, Bt, b, c_prev, h_out, c_out);
    ln_kernel<<<MROWS / 4, 256, 0, stream>>>(h_out, ln_w, ln_b);
}

// Round 3
// 246.599 us; speedup vs baseline: 1.0216x; 1.0028x over previous
//
#include <hip/hip_runtime.h>
#include <cstdint>
#include <cstddef>

typedef unsigned short ushort_t;
typedef __attribute__((ext_vector_type(8))) short bf16x8;
typedef __attribute__((ext_vector_type(4))) float f32x4;

#define MROWS 16384
#define KDIM  1024
#define NDIM  2048
#define HDIM  512
#define NTILE 16            // K tiles of 64

static __device__ __forceinline__ unsigned short f2bf(float f) {
    unsigned int u = __float_as_uint(f);
    u += 0x7fffu + ((u >> 16) & 1u);   // round-to-nearest-even
    return (unsigned short)(u >> 16);
}

static __device__ __forceinline__ float sigmoid_f(float x) {
    return 1.0f / (1.0f + __expf(-x));
}
static __device__ __forceinline__ float tanh_f(float x) {
    float t = __expf(2.0f * x);
    return 1.0f - 2.0f / (t + 1.0f);   // saturates cleanly at +/-1 for large |x|
}

// ---------------------------------------------------------------------------
// Pass 0 (merged): blocks [0,8192): A = bf16(concat(x,h_prev)) [16384][1024]
//                  blocks [8192,8704): Bt via LDS transpose
//                  Bt[n'][k] = bf16(Wcat[k][col]), n' = 4h+g, col = g*512+h
// ---------------------------------------------------------------------------
__global__ __launch_bounds__(256) void pack_ab(const float* __restrict__ x,
                                               const float* __restrict__ hp,
                                               const float* __restrict__ Wi,
                                               const float* __restrict__ Wh,
                                               ushort_t* __restrict__ A,
                                               ushort_t* __restrict__ Bt) {
    __shared__ ushort_t sm[64][72];                 // pack_b transpose tile (+8 pad)
    const int tid = threadIdx.x;
    if (blockIdx.x < 8192) {
        int t = blockIdx.x * 256 + tid;             // 8 elems per thread
        int row = t >> 7;
        int kc = (t & 127) << 3;                    // wave-uniform x vs hp branch
        const float* src = (kc < 512) ? (x + (size_t)row * 512 + kc)
                                      : (hp + (size_t)row * 512 + (kc - 512));
        float4 v0 = ((const float4*)src)[0];
        float4 v1 = ((const float4*)src)[1];
        ushort_t o[8] __attribute__((aligned(16)));
        o[0] = f2bf(v0.x); o[1] = f2bf(v0.y); o[2] = f2bf(v0.z); o[3] = f2bf(v0.w);
        o[4] = f2bf(v1.x); o[5] = f2bf(v1.y); o[6] = f2bf(v1.z); o[7] = f2bf(v1.w);
        *((uint4*)(A + (size_t)row * KDIM + kc)) = *((const uint4*)o);
    } else {
        int b2 = blockIdx.x - 8192;                 // 0..511
        int kt = b2 >> 5;                           // k-tile 0..15 (64 rows each)
        int ct = b2 & 31;                           // col-tile 0..31 (64 cols each)
        const float* W = (kt < 8) ? (Wi + (size_t)(kt * 64) * NDIM)
                                  : (Wh + (size_t)((kt - 8) * 64) * NDIM);
        // coalesced 64x64 fp32 tile load -> bf16 LDS
        int c0 = (tid & 15) * 4;
        int r0 = tid >> 4;                          // 0..15
#pragma unroll
        for (int r = 0; r < 4; ++r) {
            int krow = r * 16 + r0;
            float4 v = *((const float4*)(W + (size_t)krow * NDIM + ct * 64 + c0));
            sm[krow][c0 + 0] = f2bf(v.x);
            sm[krow][c0 + 1] = f2bf(v.y);
            sm[krow][c0 + 2] = f2bf(v.z);
            sm[krow][c0 + 3] = f2bf(v.w);
        }
        __syncthreads();
        int g = (ct * 64) >> 9;                     // gate 0..3 (tile never spans g)
        int h0 = ct * 64 - g * 512;
#pragma unroll
        for (int q = tid; q < 512; q += 256) {
            int cc = q >> 3;                        // col within tile
            int kc = (q & 7) * 8;                   // k chunk within tile
            ushort_t o[8] __attribute__((aligned(16)));
#pragma unroll
            for (int j = 0; j < 8; ++j) o[j] = sm[kc + j][cc];
            int np = 4 * (h0 + cc) + g;
            *((uint4*)(Bt + (size_t)np * KDIM + kt * 64 + kc)) = *((const uint4*)o);
        }
    }
}

// ---------------------------------------------------------------------------
// Pass 1: 256x256-tile bf16 MFMA GEMM, 4-phase/K-tile schedule with staging
// spread into the phases (template-faithful), not burst at the boundary.
//
// Phase order per K-tile t (buf p = t&1), wave quadrants of its 128x64 tile:
//   P1: ds_read A(mh0) 8 + B(nh0) 4   | MFMA m0n0 (16)
//   P2: ds_read B(nh1) 4              | MFMA m0n1 (16)   -> ALL B reads of buf p retired
//   P3: ds_read A(mh1) 8, STAGE_B(t+2)| MFMA m1n1 (16)   -> ALL A reads of buf p retired
//   P4: STAGE_A(t+2)                  | MFMA m1n0 (16, reuses b0 regs)
//   closing: s_waitcnt vmcnt(8) + s_barrier   (t+2's 8 loads in flight =>
//            tile t+1 guaranteed landed; never vmcnt(0) in steady state)
//
// WAR safety: STAGE_B(t+2)->buf p issued after P2's closing barrier (B region
// reads retired: lgkm FIFO is in-order and P2's MFMAs consumed the newest B
// read before the barrier). STAGE_A(t+2) issued after P3's closing barrier
// (same argument for A). Closing barriers are asm volatile w/ "memory" so no
// LDS op crosses them at compile time. RAW: tile t's data guaranteed by the
// vmcnt(8)+barrier at tile t-1's close.
// ---------------------------------------------------------------------------
__global__ __launch_bounds__(512, 2) void gemm_cell(const ushort_t* __restrict__ A,
                                                    const ushort_t* __restrict__ Bt,
                                                    const float* __restrict__ b,
                                                    const float* __restrict__ c_prev,
                                                    float* __restrict__ h_out,
                                                    float* __restrict__ c_out) {
    __shared__ ushort_t lds[2][32768];             // 128 KB: per buf A 32KB + B 32KB

    const int tid  = threadIdx.x;
    const int w    = tid >> 6;
    const int lane = tid & 63;
    const int mi   = w >> 2;                       // 0..1  (M wave row)
    const int nj   = w & 3;                        // 0..3  (N wave col)
    // XCD-aware swizzle: 512 blocks, 512%8==0 -> bijective
    int bid = blockIdx.x;
    int lid = (bid & 7) * 64 + (bid >> 3);
    const int m0 = (lid >> 3) * 256;               // 64 m-tiles
    const int n0 = (lid & 7) * 256;                // 8 n-tiles (permuted N)
    const int lr   = lane & 15;
    const int quad = lane >> 4;
    const int sw   = lr & 7;                       // read-side swizzle key

    // staging constants: LDS slot (row, ch) holds global chunk (ch ^ (row&7));
    // slot byte addr for thread = tid*16 + r*8192 (row = tid>>3 + r*64, both
    // terms 0 mod 8 so the XOR key is r-independent).
    const int trow0 = tid >> 3;
    const int chg   = (tid & 7) ^ (trow0 & 7);
    const size_t a_base = (size_t)(m0 + trow0) * KDIM + chg * 8;
    const size_t b_base = (size_t)(n0 + trow0) * KDIM + chg * 8;
    const int    l_base = tid * 16;                // byte offset, lane-linear x16

#define STAGE_A(kt, bufi) do {                                                      \
    const ushort_t* ap_ = A + a_base + (size_t)(kt) * 64;                           \
    char* al_ = (char*)&lds[bufi][0];                                               \
    _Pragma("unroll")                                                               \
    for (int r_ = 0; r_ < 4; ++r_)                                                  \
        __builtin_amdgcn_global_load_lds(                                           \
            (const __attribute__((address_space(1))) void*)(ap_ + (size_t)r_ * 64 * KDIM), \
            (__attribute__((address_space(3))) void*)(al_ + l_base + r_ * 8192),    \
            16, 0, 0);                                                              \
} while (0)
#define STAGE_B(kt, bufi) do {                                                      \
    const ushort_t* bp_ = Bt + b_base + (size_t)(kt) * 64;                          \
    char* bl_ = (char*)&lds[bufi][16384];                                           \
    _Pragma("unroll")                                                               \
    for (int r_ = 0; r_ < 4; ++r_)                                                  \
        __builtin_amdgcn_global_load_lds(                                           \
            (const __attribute__((address_space(1))) void*)(bp_ + (size_t)r_ * 64 * KDIM), \
            (__attribute__((address_space(3))) void*)(bl_ + l_base + r_ * 8192),    \
            16, 0, 0);                                                              \
} while (0)

    f32x4 acc[8][4];
#pragma unroll
    for (int i = 0; i < 8; ++i)
#pragma unroll
        for (int j = 0; j < 4; ++j) acc[i][j] = (f32x4){0.f, 0.f, 0.f, 0.f};

    // prologue: tiles 0 (buf0) and 1 (buf1) staged; wait tile 0, keep 1 in flight
    STAGE_A(0, 0); STAGE_B(0, 0);
    STAGE_A(1, 1); STAGE_B(1, 1);
    asm volatile("s_waitcnt vmcnt(8)\n\ts_barrier" ::: "memory");

#define TILE(t_, BUF_) do {                                                         \
    const ushort_t* Ab_ = &lds[BUF_][0];                                            \
    const ushort_t* Bb_ = &lds[BUF_][16384];                                        \
    bf16x8 af[4][2], b0v[2][2], b1v[2][2];                                          \
    /* ---- P1: A(mh0)+B(nh0) reads | MFMA m0n0 ---- */                             \
    _Pragma("unroll")                                                               \
    for (int t2 = 0; t2 < 4; ++t2) {                                                \
        int ra = mi * 128 + t2 * 16 + lr;                                           \
        af[t2][0] = *((const bf16x8*)(Ab_ + (ra * 8 + (quad ^ sw)) * 8));           \
        af[t2][1] = *((const bf16x8*)(Ab_ + (ra * 8 + ((4 + quad) ^ sw)) * 8));     \
    }                                                                               \
    _Pragma("unroll")                                                               \
    for (int j = 0; j < 2; ++j) {                                                   \
        int rb = nj * 64 + j * 16 + lr;                                             \
        b0v[j][0] = *((const bf16x8*)(Bb_ + (rb * 8 + (quad ^ sw)) * 8));           \
        b0v[j][1] = *((const bf16x8*)(Bb_ + (rb * 8 + ((4 + quad) ^ sw)) * 8));     \
    }                                                                               \
    __builtin_amdgcn_s_barrier();                                                   \
    __builtin_amdgcn_s_setprio(1);                                                  \
    _Pragma("unroll")                                                               \
    for (int t2 = 0; t2 < 4; ++t2)                                                  \
        _Pragma("unroll")                                                           \
        for (int j = 0; j < 2; ++j) {                                               \
            acc[t2][j] = __builtin_amdgcn_mfma_f32_16x16x32_bf16(                   \
                af[t2][0], b0v[j][0], acc[t2][j], 0, 0, 0);                         \
            acc[t2][j] = __builtin_amdgcn_mfma_f32_16x16x32_bf16(                   \
                af[t2][1], b0v[j][1], acc[t2][j], 0, 0, 0);                         \
        }                                                                           \
    __builtin_amdgcn_s_setprio(0);                                                  \
    asm volatile("s_barrier" ::: "memory");                                         \
    /* ---- P2: B(nh1) reads | MFMA m0n1 ---- */                                    \
    _Pragma("unroll")                                                               \
    for (int j = 0; j < 2; ++j) {                                                   \
        int rb = nj * 64 + (j + 2) * 16 + lr;                                       \
        b1v[j][0] = *((const bf16x8*)(Bb_ + (rb * 8 + (quad ^ sw)) * 8));           \
        b1v[j][1] = *((const bf16x8*)(Bb_ + (rb * 8 + ((4 + quad) ^ sw)) * 8));     \
    }                                                                               \
    __builtin_amdgcn_s_barrier();                                                   \
    __builtin_amdgcn_s_setprio(1);                                                  \
    _Pragma("unroll")                                                               \
    for (int t2 = 0; t2 < 4; ++t2)                                                  \
        _Pragma("unroll")                                                           \
        for (int j = 0; j < 2; ++j) {                                               \
            acc[t2][j + 2] = __builtin_amdgcn_mfma_f32_16x16x32_bf16(               \
                af[t2][0], b1v[j][0], acc[t2][j + 2], 0, 0, 0);                     \
            acc[t2][j + 2] = __builtin_amdgcn_mfma_f32_16x16x32_bf16(               \
                af[t2][1], b1v[j][1], acc[t2][j + 2], 0, 0, 0);                     \
        }                                                                           \
    __builtin_amdgcn_s_setprio(0);                                                  \
    asm volatile("s_barrier" ::: "memory");   /* B region of BUF_ now free */       \
    /* ---- P3: A(mh1) reads + STAGE_B(t+2) | MFMA m1n1 ---- */                     \
    _Pragma("unroll")                                                               \
    for (int t2 = 0; t2 < 4; ++t2) {                                                \
        int ra = mi * 128 + (t2 + 4) * 16 + lr;                                     \
        af[t2][0] = *((const bf16x8*)(Ab_ + (ra * 8 + (quad ^ sw)) * 8));           \
        af[t2][1] = *((const bf16x8*)(Ab_ + (ra * 8 + ((4 + quad) ^ sw)) * 8));     \
    }                                                                               \
    if ((t_) < NTILE - 2) STAGE_B((t_) + 2, BUF_);                                  \
    __builtin_amdgcn_s_barrier();                                                   \
    __builtin_amdgcn_s_setprio(1);                                                  \
    _Pragma("unroll")                                                               \
    for (int t2 = 0; t2 < 4; ++t2)                                                  \
        _Pragma("unroll")                                                           \
        for (int j = 0; j < 2; ++j) {                                               \
            acc[t2 + 4][j + 2] = __builtin_amdgcn_mfma_f32_16x16x32_bf16(           \
                af[t2][0], b1v[j][0], acc[t2 + 4][j + 2], 0, 0, 0);                 \
            acc[t2 + 4][j + 2] = __builtin_amdgcn_mfma_f32_16x16x32_bf16(           \
                af[t2][1], b1v[j][1], acc[t2 + 4][j + 2], 0, 0, 0);                 \
        }                                                                           \
    __builtin_amdgcn_s_setprio(0);                                                  \
    asm volatile("s_barrier" ::: "memory");   /* A region of BUF_ now free */       \
    /* ---- P4: STAGE_A(t+2) | MFMA m1n0 (reuse b0v) ---- */                        \
    if ((t_) < NTILE - 2) STAGE_A((t_) + 2, BUF_);                                  \
    __builtin_amdgcn_s_barrier();                                                   \
    __builtin_amdgcn_s_setprio(1);                                                  \
    _Pragma("unroll")                                                               \
    for (int t2 = 0; t2 < 4; ++t2)                                                  \
        _Pragma("unroll")                                                           \
        for (int j = 0; j < 2; ++j) {                                               \
            acc[t2 + 4][j] = __builtin_amdgcn_mfma_f32_16x16x32_bf16(               \
                af[t2][0], b0v[j][0], acc[t2 + 4][j], 0, 0, 0);                     \
            acc[t2 + 4][j] = __builtin_amdgcn_mfma_f32_16x16x32_bf16(               \
                af[t2][1], b0v[j][1], acc[t2 + 4][j], 0, 0, 0);                     \
        }                                                                           \
    __builtin_amdgcn_s_setprio(0);                                                  \
    if ((t_) < NTILE - 2) {                                                         \
        /* t+2's 8 loads in flight => t+1 landed; publish workgroup-wide */         \
        asm volatile("s_waitcnt vmcnt(8)\n\ts_barrier" ::: "memory");               \
    } else if ((t_) == NTILE - 2) {                                                 \
        asm volatile("s_waitcnt vmcnt(0)\n\ts_barrier" ::: "memory");               \
    } else {                                                                        \
        asm volatile("s_waitcnt lgkmcnt(0)\n\ts_barrier" ::: "memory");             \
    }                                                                               \
} while (0)

    for (int tp = 0; tp < NTILE / 2; ++tp) {
        TILE(2 * tp, 0);
        TILE(2 * tp + 1, 1);
    }
#undef TILE
#undef STAGE_A
#undef STAGE_B

    // ---- barrier-free epilogue: per-wave private 4 KB scratch in buf0 ----
    float* scr = (float*)&lds[0][0] + w * 1024;    // 16 rows x 64 cols
    const int rr = lane >> 2;                      // row within chunk
    const int hg0 = ((n0 + nj * 64) >> 2) + (lane & 3) * 4;  // 4 consecutive h
    const float4 bi4 = *((const float4*)(b + hg0));
    const float4 bff = *((const float4*)(b + 512 + hg0));
    const float4 bgg = *((const float4*)(b + 1024 + hg0));
    const float4 boo = *((const float4*)(b + 1536 + hg0));
    const float bi[4] = {bi4.x, bi4.y, bi4.z, bi4.w};
    const float bfv[4] = {bff.x, bff.y, bff.z, bff.w};
    const float bg[4] = {bgg.x, bgg.y, bgg.z, bgg.w};
    const float bo[4] = {boo.x, boo.y, boo.z, boo.w};

#pragma unroll
    for (int tm = 0; tm < 8; ++tm) {
        // write 16x64 chunk, XOR-swizzled 16B col-blocks
#pragma unroll
        for (int tn = 0; tn < 4; ++tn) {
            int c = tn * 16 + lr;
#pragma unroll
            for (int rg = 0; rg < 4; ++rg) {
                int r = quad * 4 + rg;
                int blk = (c >> 2) ^ r;            // 0..15
                scr[r * 64 + blk * 4 + (c & 3)] = acc[tm][tn][rg];
            }
        }
        // same-wave in-order DS pipe: no barrier needed
        float4 gv[4];
#pragma unroll
        for (int j = 0; j < 4; ++j) {
            int cb = (lane & 3) * 4 + j;
            gv[j] = *((const float4*)(scr + rr * 64 + (cb ^ rr) * 4));
        }
        int grow = m0 + mi * 128 + tm * 16 + rr;
        float4 cp4 = *((const float4*)(c_prev + (size_t)grow * HDIM + hg0));
        const float cpv[4] = {cp4.x, cp4.y, cp4.z, cp4.w};
        float cn[4], hv[4];
#pragma unroll
        for (int j = 0; j < 4; ++j) {
            float iv = sigmoid_f(gv[j].x + bi[j]);
            float fv = sigmoid_f(gv[j].y + bfv[j]);
            float g2 = tanh_f(gv[j].z + bg[j]);
            float ov = sigmoid_f(gv[j].w + bo[j]);
            cn[j] = fv * cpv[j] + iv * g2;
            hv[j] = ov * tanh_f(cn[j]);
        }
        float4 cno = {cn[0], cn[1], cn[2], cn[3]};
        float4 hvo = {hv[0], hv[1], hv[2], hv[3]};
        *((float4*)(c_out + (size_t)grow * HDIM + hg0)) = cno;
        *((float4*)(h_out + (size_t)grow * HDIM + hg0)) = hvo;
    }
}

// ---------------------------------------------------------------------------
// Pass 2: in-place row-wise LayerNorm on h (one wave per 512-elem row)
// ---------------------------------------------------------------------------
__global__ __launch_bounds__(256) void ln_kernel(float* __restrict__ h,
                                                 const float* __restrict__ lw,
                                                 const float* __restrict__ lb) {
    int w = threadIdx.x >> 6;
    int lane = threadIdx.x & 63;
    int row = blockIdx.x * 4 + w;
    float* p = h + (size_t)row * HDIM + lane * 8;
    float4 a = ((const float4*)p)[0];
    float4 c = ((const float4*)p)[1];
    float s  = a.x + a.y + a.z + a.w + c.x + c.y + c.z + c.w;
    float ss = a.x * a.x + a.y * a.y + a.z * a.z + a.w * a.w +
               c.x * c.x + c.y * c.y + c.z * c.z + c.w * c.w;
#pragma unroll
    for (int off = 32; off > 0; off >>= 1) {
        s  += __shfl_xor(s, off);
        ss += __shfl_xor(ss, off);
    }
    float mu = s * (1.0f / 512.0f);
    float var = ss * (1.0f / 512.0f) - mu * mu;
    float rstd = rsqrtf(var + 1e-5f);
    const float* wp = lw + lane * 8;
    const float* bp = lb + lane * 8;
    float4 w0 = ((const float4*)wp)[0];
    float4 w1 = ((const float4*)wp)[1];
    float4 b0 = ((const float4*)bp)[0];
    float4 b1 = ((const float4*)bp)[1];
    a.x = (a.x - mu) * rstd * w0.x + b0.x;
    a.y = (a.y - mu) * rstd * w0.y + b0.y;
    a.z = (a.z - mu) * rstd * w0.z + b0.z;
    a.w = (a.w - mu) * rstd * w0.w + b0.w;
    c.x = (c.x - mu) * rstd * w1.x + b1.x;
    c.y = (c.y - mu) * rstd * w1.y + b1.y;
    c.z = (c.z - mu) * rstd * w1.z + b1.z;
    c.w = (c.w - mu) * rstd * w1.w + b1.w;
    ((float4*)p)[0] = a;
    ((float4*)p)[1] = c;
}

extern "C" void kernel_launch(void* const* d_in, const int* in_sizes, int n_in,
                              void* d_out, int out_size, void* d_ws, size_t ws_size,
                              hipStream_t stream) {
    const float* x      = (const float*)d_in[0];
    const float* h_prev = (const float*)d_in[1];
    const float* c_prev = (const float*)d_in[2];
    const float* W_i    = (const float*)d_in[3];
    const float* W_h    = (const float*)d_in[4];
    const float* b      = (const float*)d_in[5];
    const float* ln_w   = (const float*)d_in[6];
    const float* ln_b   = (const float*)d_in[7];

    float* h_out = (float*)d_out;                       // [16384][512]
    float* c_out = h_out + (size_t)MROWS * HDIM;        // [16384][512]

    ushort_t* A  = (ushort_t*)d_ws;                     // 32 MB
    ushort_t* Bt = A + (size_t)MROWS * KDIM;            // 4 MB

    pack_ab<<<8192 + 512, 256, 0, stream>>>(x, h_prev, W_i, W_h, A, Bt);
    gemm_cell<<<512, 512, 0, stream>>>(A, Bt, b, c_prev, h_out, c_out);
    ln_kernel<<<MROWS / 4, 256, 0, stream>>>(h_out, ln_w, ln_b);
}

// Round 4
// 245.180 us; speedup vs baseline: 1.0276x; 1.0058x over previous
//
#include <hip/hip_runtime.h>
#include <cstdint>
#include <cstddef>

typedef unsigned short ushort_t;
typedef __attribute__((ext_vector_type(8))) short bf16x8;
typedef __attribute__((ext_vector_type(4))) float f32x4;

#define MROWS 16384
#define KDIM  1024
#define NDIM  2048
#define HDIM  512
#define NTILE 16            // K tiles of 64

static __device__ __forceinline__ unsigned short f2bf(float f) {
    unsigned int u = __float_as_uint(f);
    u += 0x7fffu + ((u >> 16) & 1u);   // round-to-nearest-even
    return (unsigned short)(u >> 16);
}

static __device__ __forceinline__ float sigmoid_f(float x) {
    return 1.0f / (1.0f + __expf(-x));
}
static __device__ __forceinline__ float tanh_f(float x) {
    float t = __expf(2.0f * x);
    return 1.0f - 2.0f / (t + 1.0f);   // saturates cleanly at +/-1 for large |x|
}

// ---------------------------------------------------------------------------
// Pass 0 (merged): blocks [0,8192): A = bf16(concat(x,h_prev)) [16384][1024]
//                  blocks [8192,8704): Bt via LDS transpose
//                  Bt[n'][k] = bf16(Wcat[k][col]), n' = 4h+g, col = g*512+h
// ---------------------------------------------------------------------------
__global__ __launch_bounds__(256) void pack_ab(const float* __restrict__ x,
                                               const float* __restrict__ hp,
                                               const float* __restrict__ Wi,
                                               const float* __restrict__ Wh,
                                               ushort_t* __restrict__ A,
                                               ushort_t* __restrict__ Bt) {
    __shared__ ushort_t sm[64][72];                 // pack_b transpose tile (+8 pad)
    const int tid = threadIdx.x;
    if (blockIdx.x < 8192) {
        int t = blockIdx.x * 256 + tid;             // 8 elems per thread
        int row = t >> 7;
        int kc = (t & 127) << 3;                    // wave-uniform x vs hp branch
        const float* src = (kc < 512) ? (x + (size_t)row * 512 + kc)
                                      : (hp + (size_t)row * 512 + (kc - 512));
        float4 v0 = ((const float4*)src)[0];
        float4 v1 = ((const float4*)src)[1];
        ushort_t o[8] __attribute__((aligned(16)));
        o[0] = f2bf(v0.x); o[1] = f2bf(v0.y); o[2] = f2bf(v0.z); o[3] = f2bf(v0.w);
        o[4] = f2bf(v1.x); o[5] = f2bf(v1.y); o[6] = f2bf(v1.z); o[7] = f2bf(v1.w);
        *((uint4*)(A + (size_t)row * KDIM + kc)) = *((const uint4*)o);
    } else {
        int b2 = blockIdx.x - 8192;                 // 0..511
        int kt = b2 >> 5;                           // k-tile 0..15 (64 rows each)
        int ct = b2 & 31;                           // col-tile 0..31 (64 cols each)
        const float* W = (kt < 8) ? (Wi + (size_t)(kt * 64) * NDIM)
                                  : (Wh + (size_t)((kt - 8) * 64) * NDIM);
        // coalesced 64x64 fp32 tile load -> bf16 LDS
        int c0 = (tid & 15) * 4;
        int r0 = tid >> 4;                          // 0..15
#pragma unroll
        for (int r = 0; r < 4; ++r) {
            int krow = r * 16 + r0;
            float4 v = *((const float4*)(W + (size_t)krow * NDIM + ct * 64 + c0));
            sm[krow][c0 + 0] = f2bf(v.x);
            sm[krow][c0 + 1] = f2bf(v.y);
            sm[krow][c0 + 2] = f2bf(v.z);
            sm[krow][c0 + 3] = f2bf(v.w);
        }
        __syncthreads();
        int g = (ct * 64) >> 9;                     // gate 0..3 (tile never spans g)
        int h0 = ct * 64 - g * 512;
#pragma unroll
        for (int q = tid; q < 512; q += 256) {
            int cc = q >> 3;                        // col within tile
            int kc = (q & 7) * 8;                   // k chunk within tile
            ushort_t o[8] __attribute__((aligned(16)));
#pragma unroll
            for (int j = 0; j < 8; ++j) o[j] = sm[kc + j][cc];
            int np = 4 * (h0 + cc) + g;
            *((uint4*)(Bt + (size_t)np * KDIM + kt * 64 + kc)) = *((const uint4*)o);
        }
    }
}

// ---------------------------------------------------------------------------
// Pass 1: 256x256-tile bf16 MFMA GEMM, 4-phase K-tile schedule with only the
// WAR-critical barriers (4/tile vs R3's 8) and staging spread {2,2,4}.
//
// Per tile t (buf p = t&1), phase order m0n0 -> m0n1 -> m1n0 -> m1n1 (so b0v
// dies in P3 and af regs are reused for af4-7: 16 live frags, VGPR<=128):
//   P1: read af0-3 (8) + b0v (4); MFMA m0n0;        B1; stage A-even(t+2)
//   P2: read b1v (4);             MFMA m0n1;        B2; stage B-01 (t+2)
//   P3: read af4-7 (8);           MFMA m1n0;  lgkm0+B3; stage B-23+A-odd(t+2)
//   P4: (regs only)               MFMA m1n1;  vmcnt(8)+B4
//
// WAR proofs (lgkm FIFO in-order; barrier = all waves arrived):
//  - A-even slots (rows 0-63,128-191) are read ONLY in P1 (both k-halves);
//    each wave's P1 MFMAs consume its newest read -> all 12 reads executed
//    before that wave reaches B1; B1 publishes -> stage after B1 is safe.
//  - B slots: b0v read P1, b1v read+consumed P2 -> all B reads executed
//    before B2 -> stage B after B2 safe.
//  - A-odd slots read in P3; explicit lgkmcnt(0) before B3 -> safe.
//  - vmcnt(8)+B4: exactly t+2's 8 loads in flight => t+1 landed, published.
// All waits/barriers are single asm volatile blocks w/ "memory" clobbers.
// ---------------------------------------------------------------------------
__global__ __launch_bounds__(512, 2) void gemm_cell(const ushort_t* __restrict__ A,
                                                    const ushort_t* __restrict__ Bt,
                                                    const float* __restrict__ b,
                                                    const float* __restrict__ c_prev,
                                                    float* __restrict__ h_out,
                                                    float* __restrict__ c_out) {
    __shared__ ushort_t lds[2][32768];             // 128 KB: per buf A 32KB + B 32KB

    const int tid  = threadIdx.x;
    const int w    = tid >> 6;
    const int lane = tid & 63;
    const int mi   = w >> 2;                       // 0..1  (M wave row)
    const int nj   = w & 3;                        // 0..3  (N wave col)
    // XCD-aware swizzle: 512 blocks, 512%8==0 -> bijective
    int bid = blockIdx.x;
    int lid = (bid & 7) * 64 + (bid >> 3);
    const int m0 = (lid >> 3) * 256;               // 64 m-tiles
    const int n0 = (lid & 7) * 256;                // 8 n-tiles (permuted N)
    const int lr   = lane & 15;
    const int quad = lane >> 4;
    const int sw   = lr & 7;                       // read-side swizzle key

    // staging constants: LDS slot (row, ch) holds global chunk (ch ^ (row&7));
    // slot byte addr for thread = tid*16 + r*8192 (row = tid>>3 + r*64, both
    // terms 0 mod 8 so the XOR key is r-independent).
    const int trow0 = tid >> 3;
    const int chg   = (tid & 7) ^ (trow0 & 7);
    const size_t a_base = (size_t)(m0 + trow0) * KDIM + chg * 8;
    const size_t b_base = (size_t)(n0 + trow0) * KDIM + chg * 8;
    const int    l_base = tid * 16;                // byte offset, lane-linear x16

#define STAGE_A_SLOT(kt, bufi, r_)                                              \
    __builtin_amdgcn_global_load_lds(                                           \
        (const __attribute__((address_space(1))) void*)(A + a_base +            \
            (size_t)(kt) * 64 + (size_t)(r_) * 64 * KDIM),                      \
        (__attribute__((address_space(3))) void*)((char*)&lds[bufi][0] +        \
            l_base + (r_) * 8192), 16, 0, 0)
#define STAGE_B_SLOT(kt, bufi, r_)                                              \
    __builtin_amdgcn_global_load_lds(                                           \
        (const __attribute__((address_space(1))) void*)(Bt + b_base +           \
            (size_t)(kt) * 64 + (size_t)(r_) * 64 * KDIM),                      \
        (__attribute__((address_space(3))) void*)((char*)&lds[bufi][16384] +    \
            l_base + (r_) * 8192), 16, 0, 0)

    f32x4 acc[8][4];
#pragma unroll
    for (int i = 0; i < 8; ++i)
#pragma unroll
        for (int j = 0; j < 4; ++j) acc[i][j] = (f32x4){0.f, 0.f, 0.f, 0.f};

    // prologue: tiles 0 (buf0) and 1 (buf1) staged; wait tile 0, keep 1 in flight
    STAGE_A_SLOT(0, 0, 0); STAGE_A_SLOT(0, 0, 1); STAGE_A_SLOT(0, 0, 2); STAGE_A_SLOT(0, 0, 3);
    STAGE_B_SLOT(0, 0, 0); STAGE_B_SLOT(0, 0, 1); STAGE_B_SLOT(0, 0, 2); STAGE_B_SLOT(0, 0, 3);
    STAGE_A_SLOT(1, 1, 0); STAGE_A_SLOT(1, 1, 1); STAGE_A_SLOT(1, 1, 2); STAGE_A_SLOT(1, 1, 3);
    STAGE_B_SLOT(1, 1, 0); STAGE_B_SLOT(1, 1, 1); STAGE_B_SLOT(1, 1, 2); STAGE_B_SLOT(1, 1, 3);
    asm volatile("s_waitcnt vmcnt(8)\n\ts_barrier" ::: "memory");

#define TILE(t_, BUF_) do {                                                         \
    const ushort_t* Ab_ = &lds[BUF_][0];                                            \
    const ushort_t* Bb_ = &lds[BUF_][16384];                                        \
    bf16x8 af[4][2], b0v[2][2], b1v[2][2];                                          \
    /* ---- P1: read af0-3 (both k-halves) + b0v | MFMA m0n0 ---- */                \
    _Pragma("unroll")                                                               \
    for (int t2 = 0; t2 < 4; ++t2) {                                                \
        int ra = mi * 128 + t2 * 16 + lr;                                           \
        af[t2][0] = *((const bf16x8*)(Ab_ + (ra * 8 + (quad ^ sw)) * 8));           \
        af[t2][1] = *((const bf16x8*)(Ab_ + (ra * 8 + ((4 + quad) ^ sw)) * 8));     \
    }                                                                               \
    _Pragma("unroll")                                                               \
    for (int j = 0; j < 2; ++j) {                                                   \
        int rb = nj * 64 + j * 16 + lr;                                             \
        b0v[j][0] = *((const bf16x8*)(Bb_ + (rb * 8 + (quad ^ sw)) * 8));           \
        b0v[j][1] = *((const bf16x8*)(Bb_ + (rb * 8 + ((4 + quad) ^ sw)) * 8));     \
    }                                                                               \
    __builtin_amdgcn_s_setprio(1);                                                  \
    _Pragma("unroll")                                                               \
    for (int t2 = 0; t2 < 4; ++t2)                                                  \
        _Pragma("unroll")                                                           \
        for (int j = 0; j < 2; ++j) {                                               \
            acc[t2][j] = __builtin_amdgcn_mfma_f32_16x16x32_bf16(                   \
                af[t2][0], b0v[j][0], acc[t2][j], 0, 0, 0);                         \
            acc[t2][j] = __builtin_amdgcn_mfma_f32_16x16x32_bf16(                   \
                af[t2][1], b0v[j][1], acc[t2][j], 0, 0, 0);                         \
        }                                                                           \
    __builtin_amdgcn_s_setprio(0);                                                  \
    asm volatile("s_barrier" ::: "memory");       /* B1: A-even reads retired */    \
    if ((t_) < NTILE - 2) { STAGE_A_SLOT((t_) + 2, BUF_, 0);                        \
                            STAGE_A_SLOT((t_) + 2, BUF_, 2); }                      \
    /* ---- P2: read b1v | MFMA m0n1 ---- */                                        \
    _Pragma("unroll")                                                               \
    for (int j = 0; j < 2; ++j) {                                                   \
        int rb = nj * 64 + (j + 2) * 16 + lr;                                       \
        b1v[j][0] = *((const bf16x8*)(Bb_ + (rb * 8 + (quad ^ sw)) * 8));           \
        b1v[j][1] = *((const bf16x8*)(Bb_ + (rb * 8 + ((4 + quad) ^ sw)) * 8));     \
    }                                                                               \
    __builtin_amdgcn_s_setprio(1);                                                  \
    _Pragma("unroll")                                                               \
    for (int t2 = 0; t2 < 4; ++t2)                                                  \
        _Pragma("unroll")                                                           \
        for (int j = 0; j < 2; ++j) {                                               \
            acc[t2][j + 2] = __builtin_amdgcn_mfma_f32_16x16x32_bf16(               \
                af[t2][0], b1v[j][0], acc[t2][j + 2], 0, 0, 0);                     \
            acc[t2][j + 2] = __builtin_amdgcn_mfma_f32_16x16x32_bf16(               \
                af[t2][1], b1v[j][1], acc[t2][j + 2], 0, 0, 0);                     \
        }                                                                           \
    __builtin_amdgcn_s_setprio(0);                                                  \
    asm volatile("s_barrier" ::: "memory");       /* B2: all B reads retired */     \
    if ((t_) < NTILE - 2) { STAGE_B_SLOT((t_) + 2, BUF_, 0);                        \
                            STAGE_B_SLOT((t_) + 2, BUF_, 1); }                      \
    /* ---- P3: read af4-7 (reuse af regs) | MFMA m1n0 (b0v dies here) ---- */      \
    _Pragma("unroll")                                                               \
    for (int t2 = 0; t2 < 4; ++t2) {                                                \
        int ra = mi * 128 + (t2 + 4) * 16 + lr;                                     \
        af[t2][0] = *((const bf16x8*)(Ab_ + (ra * 8 + (quad ^ sw)) * 8));           \
        af[t2][1] = *((const bf16x8*)(Ab_ + (ra * 8 + ((4 + quad) ^ sw)) * 8));     \
    }                                                                               \
    __builtin_amdgcn_s_setprio(1);                                                  \
    _Pragma("unroll")                                                               \
    for (int t2 = 0; t2 < 4; ++t2)                                                  \
        _Pragma("unroll")                                                           \
        for (int j = 0; j < 2; ++j) {                                               \
            acc[t2 + 4][j] = __builtin_amdgcn_mfma_f32_16x16x32_bf16(               \
                af[t2][0], b0v[j][0], acc[t2 + 4][j], 0, 0, 0);                     \
            acc[t2 + 4][j] = __builtin_amdgcn_mfma_f32_16x16x32_bf16(               \
                af[t2][1], b0v[j][1], acc[t2 + 4][j], 0, 0, 0);                     \
        }                                                                           \
    __builtin_amdgcn_s_setprio(0);                                                  \
    asm volatile("s_waitcnt lgkmcnt(0)\n\ts_barrier" ::: "memory"); /* B3 */        \
    if ((t_) < NTILE - 2) { STAGE_B_SLOT((t_) + 2, BUF_, 2);                        \
                            STAGE_B_SLOT((t_) + 2, BUF_, 3);                        \
                            STAGE_A_SLOT((t_) + 2, BUF_, 1);                        \
                            STAGE_A_SLOT((t_) + 2, BUF_, 3); }                      \
    /* ---- P4: MFMA m1n1 (registers only; covers the vmcnt wait) ---- */           \
    __builtin_amdgcn_s_setprio(1);                                                  \
    _Pragma("unroll")                                                               \
    for (int t2 = 0; t2 < 4; ++t2)                                                  \
        _Pragma("unroll")                                                           \
        for (int j = 0; j < 2; ++j) {                                               \
            acc[t2 + 4][j + 2] = __builtin_amdgcn_mfma_f32_16x16x32_bf16(           \
                af[t2][0], b1v[j][0], acc[t2 + 4][j + 2], 0, 0, 0);                 \
            acc[t2 + 4][j + 2] = __builtin_amdgcn_mfma_f32_16x16x32_bf16(           \
                af[t2][1], b1v[j][1], acc[t2 + 4][j + 2], 0, 0, 0);                 \
        }                                                                           \
    __builtin_amdgcn_s_setprio(0);                                                  \
    if ((t_) < NTILE - 2) {                                                         \
        /* B4: t+2's 8 loads in flight => t+1 landed; publish workgroup-wide */     \
        asm volatile("s_waitcnt vmcnt(8)\n\ts_barrier" ::: "memory");               \
    } else if ((t_) == NTILE - 2) {                                                 \
        asm volatile("s_waitcnt vmcnt(0)\n\ts_barrier" ::: "memory");               \
    } else {                                                                        \
        asm volatile("s_waitcnt lgkmcnt(0)\n\ts_barrier" ::: "memory");             \
    }                                                                               \
} while (0)

    for (int tp = 0; tp < NTILE / 2; ++tp) {
        TILE(2 * tp, 0);
        TILE(2 * tp + 1, 1);
    }
#undef TILE
#undef STAGE_A_SLOT
#undef STAGE_B_SLOT

    // ---- barrier-free epilogue: per-wave private 4 KB scratch in buf0 ----
    float* scr = (float*)&lds[0][0] + w * 1024;    // 16 rows x 64 cols
    const int rr = lane >> 2;                      // row within chunk
    const int hg0 = ((n0 + nj * 64) >> 2) + (lane & 3) * 4;  // 4 consecutive h
    const float4 bi4 = *((const float4*)(b + hg0));
    const float4 bff = *((const float4*)(b + 512 + hg0));
    const float4 bgg = *((const float4*)(b + 1024 + hg0));
    const float4 boo = *((const float4*)(b + 1536 + hg0));
    const float bi[4] = {bi4.x, bi4.y, bi4.z, bi4.w};
    const float bfv[4] = {bff.x, bff.y, bff.z, bff.w};
    const float bg[4] = {bgg.x, bgg.y, bgg.z, bgg.w};
    const float bo[4] = {boo.x, boo.y, boo.z, boo.w};

#pragma unroll
    for (int tm = 0; tm < 8; ++tm) {
        // write 16x64 chunk, XOR-swizzled 16B col-blocks
#pragma unroll
        for (int tn = 0; tn < 4; ++tn) {
            int c = tn * 16 + lr;
#pragma unroll
            for (int rg = 0; rg < 4; ++rg) {
                int r = quad * 4 + rg;
                int blk = (c >> 2) ^ r;            // 0..15
                scr[r * 64 + blk * 4 + (c & 3)] = acc[tm][tn][rg];
            }
        }
        // same-wave in-order DS pipe: no barrier needed
        float4 gv[4];
#pragma unroll
        for (int j = 0; j < 4; ++j) {
            int cb = (lane & 3) * 4 + j;
            gv[j] = *((const float4*)(scr + rr * 64 + (cb ^ rr) * 4));
        }
        int grow = m0 + mi * 128 + tm * 16 + rr;
        float4 cp4 = *((const float4*)(c_prev + (size_t)grow * HDIM + hg0));
        const float cpv[4] = {cp4.x, cp4.y, cp4.z, cp4.w};
        float cn[4], hv[4];
#pragma unroll
        for (int j = 0; j < 4; ++j) {
            float iv = sigmoid_f(gv[j].x + bi[j]);
            float fv = sigmoid_f(gv[j].y + bfv[j]);
            float g2 = tanh_f(gv[j].z + bg[j]);
            float ov = sigmoid_f(gv[j].w + bo[j]);
            cn[j] = fv * cpv[j] + iv * g2;
            hv[j] = ov * tanh_f(cn[j]);
        }
        float4 cno = {cn[0], cn[1], cn[2], cn[3]};
        float4 hvo = {hv[0], hv[1], hv[2], hv[3]};
        *((float4*)(c_out + (size_t)grow * HDIM + hg0)) = cno;
        *((float4*)(h_out + (size_t)grow * HDIM + hg0)) = hvo;
    }
}

// ---------------------------------------------------------------------------
// Pass 2: in-place row-wise LayerNorm on h (one wave per 512-elem row)
// ---------------------------------------------------------------------------
__global__ __launch_bounds__(256) void ln_kernel(float* __restrict__ h,
                                                 const float* __restrict__ lw,
                                                 const float* __restrict__ lb) {
    int w = threadIdx.x >> 6;
    int lane = threadIdx.x & 63;
    int row = blockIdx.x * 4 + w;
    float* p = h + (size_t)row * HDIM + lane * 8;
    float4 a = ((const float4*)p)[0];
    float4 c = ((const float4*)p)[1];
    float s  = a.x + a.y + a.z + a.w + c.x + c.y + c.z + c.w;
    float ss = a.x * a.x + a.y * a.y + a.z * a.z + a.w * a.w +
               c.x * c.x + c.y * c.y + c.z * c.z + c.w * c.w;
#pragma unroll
    for (int off = 32; off > 0; off >>= 1) {
        s  += __shfl_xor(s, off);
        ss += __shfl_xor(ss, off);
    }
    float mu = s * (1.0f / 512.0f);
    float var = ss * (1.0f / 512.0f) - mu * mu;
    float rstd = rsqrtf(var + 1e-5f);
    const float* wp = lw + lane * 8;
    const float* bp = lb + lane * 8;
    float4 w0 = ((const float4*)wp)[0];
    float4 w1 = ((const float4*)wp)[1];
    float4 b0 = ((const float4*)bp)[0];
    float4 b1 = ((const float4*)bp)[1];
    a.x = (a.x - mu) * rstd * w0.x + b0.x;
    a.y = (a.y - mu) * rstd * w0.y + b0.y;
    a.z = (a.z - mu) * rstd * w0.z + b0.z;
    a.w = (a.w - mu) * rstd * w0.w + b0.w;
    c.x = (c.x - mu) * rstd * w1.x + b1.x;
    c.y = (c.y - mu) * rstd * w1.y + b1.y;
    c.z = (c.z - mu) * rstd * w1.z + b1.z;
    c.w = (c.w - mu) * rstd * w1.w + b1.w;
    ((float4*)p)[0] = a;
    ((float4*)p)[1] = c;
}

extern "C" void kernel_launch(void* const* d_in, const int* in_sizes, int n_in,
                              void* d_out, int out_size, void* d_ws, size_t ws_size,
                              hipStream_t stream) {
    const float* x      = (const float*)d_in[0];
    const float* h_prev = (const float*)d_in[1];
    const float* c_prev = (const float*)d_in[2];
    const float* W_i    = (const float*)d_in[3];
    const float* W_h    = (const float*)d_in[4];
    const float* b      = (const float*)d_in[5];
    const float* ln_w   = (const float*)d_in[6];
    const float* ln_b   = (const float*)d_in[7];

    float* h_out = (float*)d_out;                       // [16384][512]
    float* c_out = h_out + (size_t)MROWS * HDIM;        // [16384][512]

    ushort_t* A  = (ushort_t*)d_ws;                     // 32 MB
    ushort_t* Bt = A + (size_t)MROWS * KDIM;            // 4 MB

    pack_ab<<<8192 + 512, 256, 0, stream>>>(x, h_prev, W_i, W_h, A, Bt);
    gemm_cell<<<512, 512, 0, stream>>>(A, Bt, b, c_prev, h_out, c_out);
    ln_kernel<<<MROWS / 4, 256, 0, stream>>>(h_out, ln_w, ln_b);
}

// Round 5
// 243.933 us; speedup vs baseline: 1.0328x; 1.0051x over previous
//
#include <hip/hip_runtime.h>
#include <cstdint>
#include <cstddef>

typedef unsigned short ushort_t;
typedef __attribute__((ext_vector_type(8))) short bf16x8;
typedef __attribute__((ext_vector_type(4))) float f32x4;

#define MROWS 16384
#define KDIM  1024
#define NDIM  2048
#define HDIM  512
#define NTILE 16            // K tiles of 64

static __device__ __forceinline__ unsigned short f2bf(float f) {
    unsigned int u = __float_as_uint(f);
    u += 0x7fffu + ((u >> 16) & 1u);   // round-to-nearest-even
    return (unsigned short)(u >> 16);
}

static __device__ __forceinline__ float sigmoid_f(float x) {
    return 1.0f / (1.0f + __expf(-x));
}
static __device__ __forceinline__ float tanh_f(float x) {
    float t = __expf(2.0f * x);
    return 1.0f - 2.0f / (t + 1.0f);   // saturates cleanly at +/-1 for large |x|
}

// ---------------------------------------------------------------------------
// Pass 0 (merged): blocks [0,2048): A = bf16(concat(x,h_prev)) [16384][1024]
//   grid-strided x4, 8 independent float4 loads in flight per thread (MLP).
// blocks [2048,2560): Bt via LDS transpose
//   Bt[n'][k] = bf16(Wcat[k][col]), n' = 4h+g, col = g*512+h
// ---------------------------------------------------------------------------
#define PACK_ABLK 2048
#define PACK_STRIDE (PACK_ABLK * 256)              // 524288 threads
__global__ __launch_bounds__(256) void pack_ab(const float* __restrict__ x,
                                               const float* __restrict__ hp,
                                               const float* __restrict__ Wi,
                                               const float* __restrict__ Wh,
                                               ushort_t* __restrict__ A,
                                               ushort_t* __restrict__ Bt) {
    __shared__ ushort_t sm[64][72];                 // pack_b transpose tile (+8 pad)
    const int tid = threadIdx.x;
    if (blockIdx.x < PACK_ABLK) {
        // 2,097,152 chunks of 8 elems; 4 per thread; coalesced per iteration.
        // Wave-uniform x/hp branch: lanes within a wave share (c & 64).
        int g = blockIdx.x * 256 + tid;
        float4 v[8];
#pragma unroll
        for (int s = 0; s < 4; ++s) {
            int c = g + s * PACK_STRIDE;
            int row = c >> 7;
            int kc = (c & 127) << 3;
            const float* src = (kc < 512) ? (x + (size_t)row * 512 + kc)
                                          : (hp + (size_t)row * 512 + (kc - 512));
            v[2 * s]     = ((const float4*)src)[0];
            v[2 * s + 1] = ((const float4*)src)[1];
        }
#pragma unroll
        for (int s = 0; s < 4; ++s) {
            int c = g + s * PACK_STRIDE;
            int row = c >> 7;
            int kc = (c & 127) << 3;
            ushort_t o[8] __attribute__((aligned(16)));
            o[0] = f2bf(v[2 * s].x);     o[1] = f2bf(v[2 * s].y);
            o[2] = f2bf(v[2 * s].z);     o[3] = f2bf(v[2 * s].w);
            o[4] = f2bf(v[2 * s + 1].x); o[5] = f2bf(v[2 * s + 1].y);
            o[6] = f2bf(v[2 * s + 1].z); o[7] = f2bf(v[2 * s + 1].w);
            *((uint4*)(A + (size_t)row * KDIM + kc)) = *((const uint4*)o);
        }
    } else {
        int b2 = blockIdx.x - PACK_ABLK;            // 0..511
        int kt = b2 >> 5;                           // k-tile 0..15 (64 rows each)
        int ct = b2 & 31;                           // col-tile 0..31 (64 cols each)
        const float* W = (kt < 8) ? (Wi + (size_t)(kt * 64) * NDIM)
                                  : (Wh + (size_t)((kt - 8) * 64) * NDIM);
        // coalesced 64x64 fp32 tile load -> bf16 LDS
        int c0 = (tid & 15) * 4;
        int r0 = tid >> 4;                          // 0..15
#pragma unroll
        for (int r = 0; r < 4; ++r) {
            int krow = r * 16 + r0;
            float4 v = *((const float4*)(W + (size_t)krow * NDIM + ct * 64 + c0));
            sm[krow][c0 + 0] = f2bf(v.x);
            sm[krow][c0 + 1] = f2bf(v.y);
            sm[krow][c0 + 2] = f2bf(v.z);
            sm[krow][c0 + 3] = f2bf(v.w);
        }
        __syncthreads();
        int g = (ct * 64) >> 9;                     // gate 0..3 (tile never spans g)
        int h0 = ct * 64 - g * 512;
#pragma unroll
        for (int q = tid; q < 512; q += 256) {
            int cc = q >> 3;                        // col within tile
            int kc = (q & 7) * 8;                   // k chunk within tile
            ushort_t o[8] __attribute__((aligned(16)));
#pragma unroll
            for (int j = 0; j < 8; ++j) o[j] = sm[kc + j][cc];
            int np = 4 * (h0 + cc) + g;
            *((uint4*)(Bt + (size_t)np * KDIM + kt * 64 + kc)) = *((const uint4*)o);
        }
    }
}

// ---------------------------------------------------------------------------
// Pass 1: 256x256-tile bf16 MFMA GEMM, 4-phase K-tile schedule with only the
// WAR-critical barriers (4/tile) and staging spread {2,2,4}.
// UNCHANGED from R4 (control for this round's pack/ln experiment).
//
// Per tile t (buf p = t&1), phase order m0n0 -> m0n1 -> m1n0 -> m1n1 (so b0v
// dies in P3 and af regs are reused for af4-7: 16 live frags, VGPR<=128):
//   P1: read af0-3 (8) + b0v (4); MFMA m0n0;        B1; stage A-even(t+2)
//   P2: read b1v (4);             MFMA m0n1;        B2; stage B-01 (t+2)
//   P3: read af4-7 (8);           MFMA m1n0;  lgkm0+B3; stage B-23+A-odd(t+2)
//   P4: (regs only)               MFMA m1n1;  vmcnt(8)+B4
//
// WAR proofs (lgkm FIFO in-order; barrier = all waves arrived):
//  - A-even slots are read ONLY in P1 (both k-halves); consumed before B1.
//  - B slots: b0v read P1, b1v read+consumed P2 -> stage B after B2 safe.
//  - A-odd slots read in P3; explicit lgkmcnt(0) before B3 -> safe.
//  - vmcnt(8)+B4: exactly t+2's 8 loads in flight => t+1 landed, published.
// All waits/barriers are single asm volatile blocks w/ "memory" clobbers.
// ---------------------------------------------------------------------------
__global__ __launch_bounds__(512, 2) void gemm_cell(const ushort_t* __restrict__ A,
                                                    const ushort_t* __restrict__ Bt,
                                                    const float* __restrict__ b,
                                                    const float* __restrict__ c_prev,
                                                    float* __restrict__ h_out,
                                                    float* __restrict__ c_out) {
    __shared__ ushort_t lds[2][32768];             // 128 KB: per buf A 32KB + B 32KB

    const int tid  = threadIdx.x;
    const int w    = tid >> 6;
    const int lane = tid & 63;
    const int mi   = w >> 2;                       // 0..1  (M wave row)
    const int nj   = w & 3;                        // 0..3  (N wave col)
    // XCD-aware swizzle: 512 blocks, 512%8==0 -> bijective
    int bid = blockIdx.x;
    int lid = (bid & 7) * 64 + (bid >> 3);
    const int m0 = (lid >> 3) * 256;               // 64 m-tiles
    const int n0 = (lid & 7) * 256;                // 8 n-tiles (permuted N)
    const int lr   = lane & 15;
    const int quad = lane >> 4;
    const int sw   = lr & 7;                       // read-side swizzle key

    // staging constants: LDS slot (row, ch) holds global chunk (ch ^ (row&7));
    // slot byte addr for thread = tid*16 + r*8192 (row = tid>>3 + r*64, both
    // terms 0 mod 8 so the XOR key is r-independent).
    const int trow0 = tid >> 3;
    const int chg   = (tid & 7) ^ (trow0 & 7);
    const size_t a_base = (size_t)(m0 + trow0) * KDIM + chg * 8;
    const size_t b_base = (size_t)(n0 + trow0) * KDIM + chg * 8;
    const int    l_base = tid * 16;                // byte offset, lane-linear x16

#define STAGE_A_SLOT(kt, bufi, r_)                                              \
    __builtin_amdgcn_global_load_lds(                                           \
        (const __attribute__((address_space(1))) void*)(A + a_base +            \
            (size_t)(kt) * 64 + (size_t)(r_) * 64 * KDIM),                      \
        (__attribute__((address_space(3))) void*)((char*)&lds[bufi][0] +        \
            l_base + (r_) * 8192), 16, 0, 0)
#define STAGE_B_SLOT(kt, bufi, r_)                                              \
    __builtin_amdgcn_global_load_lds(                                           \
        (const __attribute__((address_space(1))) void*)(Bt + b_base +           \
            (size_t)(kt) * 64 + (size_t)(r_) * 64 * KDIM),                      \
        (__attribute__((address_space(3))) void*)((char*)&lds[bufi][16384] +    \
            l_base + (r_) * 8192), 16, 0, 0)

    f32x4 acc[8][4];
#pragma unroll
    for (int i = 0; i < 8; ++i)
#pragma unroll
        for (int j = 0; j < 4; ++j) acc[i][j] = (f32x4){0.f, 0.f, 0.f, 0.f};

    // prologue: tiles 0 (buf0) and 1 (buf1) staged; wait tile 0, keep 1 in flight
    STAGE_A_SLOT(0, 0, 0); STAGE_A_SLOT(0, 0, 1); STAGE_A_SLOT(0, 0, 2); STAGE_A_SLOT(0, 0, 3);
    STAGE_B_SLOT(0, 0, 0); STAGE_B_SLOT(0, 0, 1); STAGE_B_SLOT(0, 0, 2); STAGE_B_SLOT(0, 0, 3);
    STAGE_A_SLOT(1, 1, 0); STAGE_A_SLOT(1, 1, 1); STAGE_A_SLOT(1, 1, 2); STAGE_A_SLOT(1, 1, 3);
    STAGE_B_SLOT(1, 1, 0); STAGE_B_SLOT(1, 1, 1); STAGE_B_SLOT(1, 1, 2); STAGE_B_SLOT(1, 1, 3);
    asm volatile("s_waitcnt vmcnt(8)\n\ts_barrier" ::: "memory");

#define TILE(t_, BUF_) do {                                                         \
    const ushort_t* Ab_ = &lds[BUF_][0];                                            \
    const ushort_t* Bb_ = &lds[BUF_][16384];                                        \
    bf16x8 af[4][2], b0v[2][2], b1v[2][2];                                          \
    /* ---- P1: read af0-3 (both k-halves) + b0v | MFMA m0n0 ---- */                \
    _Pragma("unroll")                                                               \
    for (int t2 = 0; t2 < 4; ++t2) {                                                \
        int ra = mi * 128 + t2 * 16 + lr;                                           \
        af[t2][0] = *((const bf16x8*)(Ab_ + (ra * 8 + (quad ^ sw)) * 8));           \
        af[t2][1] = *((const bf16x8*)(Ab_ + (ra * 8 + ((4 + quad) ^ sw)) * 8));     \
    }                                                                               \
    _Pragma("unroll")                                                               \
    for (int j = 0; j < 2; ++j) {                                                   \
        int rb = nj * 64 + j * 16 + lr;                                             \
        b0v[j][0] = *((const bf16x8*)(Bb_ + (rb * 8 + (quad ^ sw)) * 8));           \
        b0v[j][1] = *((const bf16x8*)(Bb_ + (rb * 8 + ((4 + quad) ^ sw)) * 8));     \
    }                                                                               \
    __builtin_amdgcn_s_setprio(1);                                                  \
    _Pragma("unroll")                                                               \
    for (int t2 = 0; t2 < 4; ++t2)                                                  \
        _Pragma("unroll")                                                           \
        for (int j = 0; j < 2; ++j) {                                               \
            acc[t2][j] = __builtin_amdgcn_mfma_f32_16x16x32_bf16(                   \
                af[t2][0], b0v[j][0], acc[t2][j], 0, 0, 0);                         \
            acc[t2][j] = __builtin_amdgcn_mfma_f32_16x16x32_bf16(                   \
                af[t2][1], b0v[j][1], acc[t2][j], 0, 0, 0);                         \
        }                                                                           \
    __builtin_amdgcn_s_setprio(0);                                                  \
    asm volatile("s_barrier" ::: "memory");       /* B1: A-even reads retired */    \
    if ((t_) < NTILE - 2) { STAGE_A_SLOT((t_) + 2, BUF_, 0);                        \
                            STAGE_A_SLOT((t_) + 2, BUF_, 2); }                      \
    /* ---- P2: read b1v | MFMA m0n1 ---- */                                        \
    _Pragma("unroll")                                                               \
    for (int j = 0; j < 2; ++j) {                                                   \
        int rb = nj * 64 + (j + 2) * 16 + lr;                                       \
        b1v[j][0] = *((const bf16x8*)(Bb_ + (rb * 8 + (quad ^ sw)) * 8));           \
        b1v[j][1] = *((const bf16x8*)(Bb_ + (rb * 8 + ((4 + quad) ^ sw)) * 8));     \
    }                                                                               \
    __builtin_amdgcn_s_setprio(1);                                                  \
    _Pragma("unroll")                                                               \
    for (int t2 = 0; t2 < 4; ++t2)                                                  \
        _Pragma("unroll")                                                           \
        for (int j = 0; j < 2; ++j) {                                               \
            acc[t2][j + 2] = __builtin_amdgcn_mfma_f32_16x16x32_bf16(               \
                af[t2][0], b1v[j][0], acc[t2][j + 2], 0, 0, 0);                     \
            acc[t2][j + 2] = __builtin_amdgcn_mfma_f32_16x16x32_bf16(               \
                af[t2][1], b1v[j][1], acc[t2][j + 2], 0, 0, 0);                     \
        }                                                                           \
    __builtin_amdgcn_s_setprio(0);                                                  \
    asm volatile("s_barrier" ::: "memory");       /* B2: all B reads retired */     \
    if ((t_) < NTILE - 2) { STAGE_B_SLOT((t_) + 2, BUF_, 0);                        \
                            STAGE_B_SLOT((t_) + 2, BUF_, 1); }                      \
    /* ---- P3: read af4-7 (reuse af regs) | MFMA m1n0 (b0v dies here) ---- */      \
    _Pragma("unroll")                                                               \
    for (int t2 = 0; t2 < 4; ++t2) {                                                \
        int ra = mi * 128 + (t2 + 4) * 16 + lr;                                     \
        af[t2][0] = *((const bf16x8*)(Ab_ + (ra * 8 + (quad ^ sw)) * 8));           \
        af[t2][1] = *((const bf16x8*)(Ab_ + (ra * 8 + ((4 + quad) ^ sw)) * 8));     \
    }                                                                               \
    __builtin_amdgcn_s_setprio(1);                                                  \
    _Pragma("unroll")                                                               \
    for (int t2 = 0; t2 < 4; ++t2)                                                  \
        _Pragma("unroll")                                                           \
        for (int j = 0; j < 2; ++j) {                                               \
            acc[t2 + 4][j] = __builtin_amdgcn_mfma_f32_16x16x32_bf16(               \
                af[t2][0], b0v[j][0], acc[t2 + 4][j], 0, 0, 0);                     \
            acc[t2 + 4][j] = __builtin_amdgcn_mfma_f32_16x16x32_bf16(               \
                af[t2][1], b0v[j][1], acc[t2 + 4][j], 0, 0, 0);                     \
        }                                                                           \
    __builtin_amdgcn_s_setprio(0);                                                  \
    asm volatile("s_waitcnt lgkmcnt(0)\n\ts_barrier" ::: "memory"); /* B3 */        \
    if ((t_) < NTILE - 2) { STAGE_B_SLOT((t_) + 2, BUF_, 2);                        \
                            STAGE_B_SLOT((t_) + 2, BUF_, 3);                        \
                            STAGE_A_SLOT((t_) + 2, BUF_, 1);                        \
                            STAGE_A_SLOT((t_) + 2, BUF_, 3); }                      \
    /* ---- P4: MFMA m1n1 (registers only; covers the vmcnt wait) ---- */           \
    __builtin_amdgcn_s_setprio(1);                                                  \
    _Pragma("unroll")                                                               \
    for (int t2 = 0; t2 < 4; ++t2)                                                  \
        _Pragma("unroll")                                                           \
        for (int j = 0; j < 2; ++j) {                                               \
            acc[t2 + 4][j + 2] = __builtin_amdgcn_mfma_f32_16x16x32_bf16(           \
                af[t2][0], b1v[j][0], acc[t2 + 4][j + 2], 0, 0, 0);                 \
            acc[t2 + 4][j + 2] = __builtin_amdgcn_mfma_f32_16x16x32_bf16(           \
                af[t2][1], b1v[j][1], acc[t2 + 4][j + 2], 0, 0, 0);                 \
        }                                                                           \
    __builtin_amdgcn_s_setprio(0);                                                  \
    if ((t_) < NTILE - 2) {                                                         \
        /* B4: t+2's 8 loads in flight => t+1 landed; publish workgroup-wide */     \
        asm volatile("s_waitcnt vmcnt(8)\n\ts_barrier" ::: "memory");               \
    } else if ((t_) == NTILE - 2) {                                                 \
        asm volatile("s_waitcnt vmcnt(0)\n\ts_barrier" ::: "memory");               \
    } else {                                                                        \
        asm volatile("s_waitcnt lgkmcnt(0)\n\ts_barrier" ::: "memory");             \
    }                                                                               \
} while (0)

    for (int tp = 0; tp < NTILE / 2; ++tp) {
        TILE(2 * tp, 0);
        TILE(2 * tp + 1, 1);
    }
#undef TILE
#undef STAGE_A_SLOT
#undef STAGE_B_SLOT

    // ---- barrier-free epilogue: per-wave private 4 KB scratch in buf0 ----
    float* scr = (float*)&lds[0][0] + w * 1024;    // 16 rows x 64 cols
    const int rr = lane >> 2;                      // row within chunk
    const int hg0 = ((n0 + nj * 64) >> 2) + (lane & 3) * 4;  // 4 consecutive h
    const float4 bi4 = *((const float4*)(b + hg0));
    const float4 bff = *((const float4*)(b + 512 + hg0));
    const float4 bgg = *((const float4*)(b + 1024 + hg0));
    const float4 boo = *((const float4*)(b + 1536 + hg0));
    const float bi[4] = {bi4.x, bi4.y, bi4.z, bi4.w};
    const float bfv[4] = {bff.x, bff.y, bff.z, bff.w};
    const float bg[4] = {bgg.x, bgg.y, bgg.z, bgg.w};
    const float bo[4] = {boo.x, boo.y, boo.z, boo.w};

#pragma unroll
    for (int tm = 0; tm < 8; ++tm) {
        // write 16x64 chunk, XOR-swizzled 16B col-blocks
#pragma unroll
        for (int tn = 0; tn < 4; ++tn) {
            int c = tn * 16 + lr;
#pragma unroll
            for (int rg = 0; rg < 4; ++rg) {
                int r = quad * 4 + rg;
                int blk = (c >> 2) ^ r;            // 0..15
                scr[r * 64 + blk * 4 + (c & 3)] = acc[tm][tn][rg];
            }
        }
        // same-wave in-order DS pipe: no barrier needed
        float4 gv[4];
#pragma unroll
        for (int j = 0; j < 4; ++j) {
            int cb = (lane & 3) * 4 + j;
            gv[j] = *((const float4*)(scr + rr * 64 + (cb ^ rr) * 4));
        }
        int grow = m0 + mi * 128 + tm * 16 + rr;
        float4 cp4 = *((const float4*)(c_prev + (size_t)grow * HDIM + hg0));
        const float cpv[4] = {cp4.x, cp4.y, cp4.z, cp4.w};
        float cn[4], hv[4];
#pragma unroll
        for (int j = 0; j < 4; ++j) {
            float iv = sigmoid_f(gv[j].x + bi[j]);
            float fv = sigmoid_f(gv[j].y + bfv[j]);
            float g2 = tanh_f(gv[j].z + bg[j]);
            float ov = sigmoid_f(gv[j].w + bo[j]);
            cn[j] = fv * cpv[j] + iv * g2;
            hv[j] = ov * tanh_f(cn[j]);
        }
        float4 cno = {cn[0], cn[1], cn[2], cn[3]};
        float4 hvo = {hv[0], hv[1], hv[2], hv[3]};
        *((float4*)(c_out + (size_t)grow * HDIM + hg0)) = cno;
        *((float4*)(h_out + (size_t)grow * HDIM + hg0)) = hvo;
    }
}

// ---------------------------------------------------------------------------
// Pass 2: in-place row-wise LayerNorm on h. 2048 blocks; each wave handles
// TWO independent rows (r, r+8192) with interleaved loads/reductions (2x ILP).
// ---------------------------------------------------------------------------
__global__ __launch_bounds__(256) void ln_kernel(float* __restrict__ h,
                                                 const float* __restrict__ lw,
                                                 const float* __restrict__ lb) {
    int w = threadIdx.x >> 6;
    int lane = threadIdx.x & 63;
    int r0 = blockIdx.x * 4 + w;                   // 0..8191
    int r1 = r0 + (MROWS >> 1);                    // 8192..16383
    float* p0 = h + (size_t)r0 * HDIM + lane * 8;
    float* p1 = h + (size_t)r1 * HDIM + lane * 8;
    float4 a0 = ((const float4*)p0)[0];
    float4 c0 = ((const float4*)p0)[1];
    float4 a1 = ((const float4*)p1)[0];
    float4 c1 = ((const float4*)p1)[1];
    const float* wp = lw + lane * 8;
    const float* bp = lb + lane * 8;
    float4 w0 = ((const float4*)wp)[0];
    float4 w1 = ((const float4*)wp)[1];
    float4 b0 = ((const float4*)bp)[0];
    float4 b1 = ((const float4*)bp)[1];

    float s0  = a0.x + a0.y + a0.z + a0.w + c0.x + c0.y + c0.z + c0.w;
    float ss0 = a0.x * a0.x + a0.y * a0.y + a0.z * a0.z + a0.w * a0.w +
                c0.x * c0.x + c0.y * c0.y + c0.z * c0.z + c0.w * c0.w;
    float s1  = a1.x + a1.y + a1.z + a1.w + c1.x + c1.y + c1.z + c1.w;
    float ss1 = a1.x * a1.x + a1.y * a1.y + a1.z * a1.z + a1.w * a1.w +
                c1.x * c1.x + c1.y * c1.y + c1.z * c1.z + c1.w * c1.w;
#pragma unroll
    for (int off = 32; off > 0; off >>= 1) {
        s0  += __shfl_xor(s0, off);
        ss0 += __shfl_xor(ss0, off);
        s1  += __shfl_xor(s1, off);
        ss1 += __shfl_xor(ss1, off);
    }
    float mu0 = s0 * (1.0f / 512.0f);
    float var0 = ss0 * (1.0f / 512.0f) - mu0 * mu0;
    float rstd0 = rsqrtf(var0 + 1e-5f);
    float mu1 = s1 * (1.0f / 512.0f);
    float var1 = ss1 * (1.0f / 512.0f) - mu1 * mu1;
    float rstd1 = rsqrtf(var1 + 1e-5f);

    a0.x = (a0.x - mu0) * rstd0 * w0.x + b0.x;
    a0.y = (a0.y - mu0) * rstd0 * w0.y + b0.y;
    a0.z = (a0.z - mu0) * rstd0 * w0.z + b0.z;
    a0.w = (a0.w - mu0) * rstd0 * w0.w + b0.w;
    c0.x = (c0.x - mu0) * rstd0 * w1.x + b1.x;
    c0.y = (c0.y - mu0) * rstd0 * w1.y + b1.y;
    c0.z = (c0.z - mu0) * rstd0 * w1.z + b1.z;
    c0.w = (c0.w - mu0) * rstd0 * w1.w + b1.w;
    a1.x = (a1.x - mu1) * rstd1 * w0.x + b0.x;
    a1.y = (a1.y - mu1) * rstd1 * w0.y + b0.y;
    a1.z = (a1.z - mu1) * rstd1 * w0.z + b0.z;
    a1.w = (a1.w - mu1) * rstd1 * w0.w + b0.w;
    c1.x = (c1.x - mu1) * rstd1 * w1.x + b1.x;
    c1.y = (c1.y - mu1) * rstd1 * w1.y + b1.y;
    c1.z = (c1.z - mu1) * rstd1 * w1.z + b1.z;
    c1.w = (c1.w - mu1) * rstd1 * w1.w + b1.w;
    ((float4*)p0)[0] = a0;
    ((float4*)p0)[1] = c0;
    ((float4*)p1)[0] = a1;
    ((float4*)p1)[1] = c1;
}

extern "C" void kernel_launch(void* const* d_in, const int* in_sizes, int n_in,
                              void* d_out, int out_size, void* d_ws, size_t ws_size,
                              hipStream_t stream) {
    const float* x      = (const float*)d_in[0];
    const float* h_prev = (const float*)d_in[1];
    const float* c_prev = (const float*)d_in[2];
    const float* W_i    = (const float*)d_in[3];
    const float* W_h    = (const float*)d_in[4];
    const float* b      = (const float*)d_in[5];
    const float* ln_w   = (const float*)d_in[6];
    const float* ln_b   = (const float*)d_in[7];

    float* h_out = (float*)d_out;                       // [16384][512]
    float* c_out = h_out + (size_t)MROWS * HDIM;        // [16384][512]

    ushort_t* A  = (ushort_t*)d_ws;                     // 32 MB
    ushort_t* Bt = A + (size_t)MROWS * KDIM;            // 4 MB

    pack_ab<<<PACK_ABLK + 512, 256, 0, stream>>>(x, h_prev, W_i, W_h, A, Bt);
    gemm_cell<<<512, 512, 0, stream>>>(A, Bt, b, c_prev, h_out, c_out);
    ln_kernel<<<MROWS / 8, 256, 0, stream>>>(h_out, ln_w, ln_b);
}